// Round 1
// baseline (197.553 us; speedup 1.0000x reference)
//
#include <hip/hip_runtime.h>
#include <hip/hip_bf16.h>

typedef __bf16 bf16_t;
typedef __bf16 bf16x8 __attribute__((ext_vector_type(8)));
typedef float  f32x4  __attribute__((ext_vector_type(4)));

#define MFMA16(A,B,C) __builtin_amdgcn_mfma_f32_16x16x32_bf16((A),(B),(C),0,0,0)

constexpr int Bn = 2, Cc = 128, Hh = 64, Wd = 64;
constexpr int N  = Hh * Wd;      // 4096 tokens per batch
constexpr int T  = Bn * N;       // 8192 tokens total
constexpr int D  = 2 * Cc;       // 256 = [real | imag] channels
constexpr float EPS = 1e-5f;
// softmax scale folded into exp2 domain: C^-0.5 * log2(e)
constexpr float SCL = 0.08838834764831845f * 1.4426950408889634f;

// ---------------- kernel 1: BN stats -> per-channel scale/shift ----------------
__global__ void k_bnstats(const float* __restrict__ x, const float* __restrict__ bn_w,
                          const float* __restrict__ bn_b, float4* __restrict__ ss) {
    int c = blockIdx.x;          // 128 blocks
    int tid = threadIdx.x;       // 256 threads
    float sr = 0.f, si = 0.f, qr = 0.f, qi = 0.f;
    for (int b = 0; b < Bn; ++b) {
        const float2* p = (const float2*)x + (size_t)(b * Cc + c) * N;
        for (int hw = tid; hw < N; hw += 256) {
            float2 v = p[hw];
            sr += v.x; si += v.y; qr += v.x * v.x; qi += v.y * v.y;
        }
    }
    #pragma unroll
    for (int d = 32; d >= 1; d >>= 1) {
        sr += __shfl_xor(sr, d); si += __shfl_xor(si, d);
        qr += __shfl_xor(qr, d); qi += __shfl_xor(qi, d);
    }
    __shared__ float red[4][4];
    int w = tid >> 6;
    if ((tid & 63) == 0) { red[w][0] = sr; red[w][1] = si; red[w][2] = qr; red[w][3] = qi; }
    __syncthreads();
    if (tid == 0) {
        sr = red[0][0] + red[1][0] + red[2][0] + red[3][0];
        si = red[0][1] + red[1][1] + red[2][1] + red[3][1];
        qr = red[0][2] + red[1][2] + red[2][2] + red[3][2];
        qi = red[0][3] + red[1][3] + red[2][3] + red[3][3];
        const float inv = 1.0f / (float)(Bn * N);
        float mr = sr * inv, mi = si * inv;
        float vr = qr * inv - mr * mr, vi = qi * inv - mi * mi;
        float scr = bn_w[c * 2 + 0] * rsqrtf(vr + EPS);
        float sci = bn_w[c * 2 + 1] * rsqrtf(vi + EPS);
        ss[c] = make_float4(scr, bn_b[c * 2 + 0] - mr * scr,
                            sci, bn_b[c * 2 + 1] - mi * sci);
    }
}

// ---- kernel 2: normalize; write xn (fp32, original layout) into d_out and
// ----           token-major bf16 XN[t][256] for the QKV GEMM --------------
__global__ void k_norm(const float* __restrict__ x, const float4* __restrict__ ss,
                       float* __restrict__ xn_out, bf16_t* __restrict__ XN) {
    __shared__ bf16_t tile[256 * 33];
    int blk = blockIdx.x;                 // 256 blocks
    int b = blk >> 7, hw0 = (blk & 127) * 32;
    int tid = threadIdx.x;
    const float2* xin = (const float2*)x;
    float2* xo = (float2*)xn_out;
    #pragma unroll
    for (int i = 0; i < 16; ++i) {
        int linear = i * 256 + tid;
        int c = linear >> 5, hwo = linear & 31;
        size_t idx = (size_t)(b * Cc + c) * N + hw0 + hwo;
        float2 v = xin[idx];
        float4 s = ss[c];
        float xr = v.x * s.x + s.y;
        float xi = v.y * s.z + s.w;
        xo[idx] = make_float2(xr, xi);
        tile[c * 33 + hwo]         = (bf16_t)xr;
        tile[(128 + c) * 33 + hwo] = (bf16_t)xi;
    }
    __syncthreads();
    const ushort* tp = (const ushort*)tile;
    #pragma unroll
    for (int i = 0; i < 8; ++i) {
        int idx = i * 256 + tid;
        int tl = idx >> 6, chunk = idx & 63;
        int j0 = chunk * 4;
        ushort4 v;
        v.x = tp[(j0 + 0) * 33 + tl];
        v.y = tp[(j0 + 1) * 33 + tl];
        v.z = tp[(j0 + 2) * 33 + tl];
        v.w = tp[(j0 + 3) * 33 + tl];
        ((ushort4*)(XN + (size_t)(b * N + hw0 + tl) * D))[chunk] = v;
    }
}

// ---- kernel 3: build combined weight matrix Wt[768][256] (bf16) + bias bt[768]
// rows: [Qr(128) Qi(128) Kr Ki Vr Vi]; real-out row = [Wr | -Wi]; imag-out = [Wi | Wr]
__global__ void k_prep(const float* __restrict__ wq, const float* __restrict__ wk,
                       const float* __restrict__ wv, const float* __restrict__ bq,
                       const float* __restrict__ bk, const float* __restrict__ bv,
                       bf16_t* __restrict__ Wt, float* __restrict__ bt) {
    int o = blockIdx.x;      // 768
    int k = threadIdx.x;     // 256
    int proj = o >> 8, oc = o & 255;
    const float* wsrc = proj == 0 ? wq : (proj == 1 ? wk : wv);
    const float* bsrc = proj == 0 ? bq : (proj == 1 ? bk : bv);
    int co = oc >> 7, oo = oc & 127;
    int c = k & 127, kc = k >> 7;
    float val;
    if (co == 0) val = (kc == 0) ? wsrc[(oo * 128 + c) * 2 + 0] : -wsrc[(oo * 128 + c) * 2 + 1];
    else         val = (kc == 0) ? wsrc[(oo * 128 + c) * 2 + 1] :  wsrc[(oo * 128 + c) * 2 + 0];
    Wt[o * 256 + k] = (bf16_t)val;
    if (k == 0) bt[o] = bsrc[oo * 2 + co];
}

// ---- kernel 4: QKV GEMM: [8192 x 256] @ [256 x 768] -> Q,K token-major bf16,
// ----           V transposed (channel-major) for attention staging ----------
__global__ __launch_bounds__(256) void k_qkv(const bf16_t* __restrict__ XN,
        const bf16_t* __restrict__ Wt, const float* __restrict__ bt,
        bf16_t* __restrict__ Q, bf16_t* __restrict__ K, bf16_t* __restrict__ V) {
    __shared__ bf16_t Wsh[64 * 264];
    int mx = blockIdx.x, ny = blockIdx.y;   // 128 x 12
    int tid = threadIdx.x;
    #pragma unroll
    for (int i = 0; i < 8; ++i) {
        int idx = i * 256 + tid;
        int row = idx >> 5, chunk = idx & 31;
        *(uint4*)&Wsh[row * 264 + chunk * 8] =
            *(const uint4*)&Wt[(size_t)(ny * 64 + row) * 256 + chunk * 8];
    }
    __syncthreads();
    int w = tid >> 6, lane = tid & 63, n15 = lane & 15, quad = lane >> 4;
    int tok = mx * 64 + w * 16;
    f32x4 acc[4] = {};
    const bf16_t* arow = XN + (size_t)(tok + n15) * D;
    #pragma unroll
    for (int ks = 0; ks < 8; ++ks) {
        bf16x8 a = *(const bf16x8*)(arow + ks * 32 + quad * 8);
        #pragma unroll
        for (int t = 0; t < 4; ++t) {
            bf16x8 bw = *(const bf16x8*)&Wsh[(t * 16 + n15) * 264 + ks * 32 + quad * 8];
            acc[t] = MFMA16(a, bw, acc[t]);
        }
    }
    int colbase = ny * 64;
    int reg = colbase >> 8;   // 0=Q, 1=K, 2=V (block-uniform)
    #pragma unroll
    for (int t = 0; t < 4; ++t) {
        int oc = colbase + t * 16 + n15;
        int j = oc & 255;
        float bias = bt[oc];
        #pragma unroll
        for (int r = 0; r < 4; ++r) {
            int tk = tok + quad * 4 + r;
            float v = acc[t][r] + bias;
            if (reg == 0)      Q[(size_t)tk * D + j] = (bf16_t)v;
            else if (reg == 1) K[(size_t)tk * D + j] = (bf16_t)v;
            else {
                int bb = tk >> 12, n = tk & (N - 1);
                V[((size_t)(bb * D + j)) * N + n] = (bf16_t)v;
            }
        }
    }
}

// ---- kernel 5: flash attention, BR=64 (4 waves x 16 rows), BC=64, key-split 4
__global__ __launch_bounds__(256, 2) void k_attn(const bf16_t* __restrict__ Q,
        const bf16_t* __restrict__ K, const bf16_t* __restrict__ V,
        float* __restrict__ Op, float* __restrict__ Mp, float* __restrict__ Lp) {
    __shared__ bf16_t Ksh[64 * 264];    // [key][chan], 528B rows
    __shared__ bf16_t Vsh[256 * 72];    // [chan][key], 144B rows
    __shared__ bf16_t Psh[4 * 16 * 72]; // wave-private P strips
    int bid = blockIdx.x;               // 512 = 2 b x 64 qtiles x 4 splits
    int sp = bid & 3, qt = (bid >> 2) & 63, b = bid >> 8;
    int tid = threadIdx.x;
    int w = tid >> 6, lane = tid & 63, n15 = lane & 15, quad = lane >> 4;

    int qtok = b * N + qt * 64 + w * 16 + n15;
    bf16x8 qf[8];
    #pragma unroll
    for (int ks = 0; ks < 8; ++ks)
        qf[ks] = *(const bf16x8*)(Q + (size_t)qtok * D + ks * 32 + quad * 8);

    f32x4 o[16] = {};
    float m_[4] = {-1e30f, -1e30f, -1e30f, -1e30f};
    float l_[4] = {0.f, 0.f, 0.f, 0.f};
    bf16_t* Pw = Psh + w * 16 * 72;

    for (int kt = 0; kt < 16; ++kt) {
        int key0 = sp * 1024 + kt * 64;
        __syncthreads();
        #pragma unroll
        for (int i = 0; i < 8; ++i) {   // stage K tile (64 keys x 256 ch)
            int idx = i * 256 + tid;
            int row = idx >> 5, chunk = idx & 31;
            *(uint4*)&Ksh[row * 264 + chunk * 8] =
                *(const uint4*)&K[((size_t)(b * N + key0 + row)) * D + chunk * 8];
        }
        #pragma unroll
        for (int i = 0; i < 8; ++i) {   // stage V tile (256 ch x 64 keys), already transposed
            int idx = i * 256 + tid;
            int ch = idx >> 3, kc = idx & 7;
            *(uint4*)&Vsh[ch * 72 + kc * 8] =
                *(const uint4*)&V[((size_t)(b * D + ch)) * N + key0 + kc * 8];
        }
        __syncthreads();

        f32x4 s[4] = {};
        #pragma unroll
        for (int ks = 0; ks < 8; ++ks) {
            #pragma unroll
            for (int t = 0; t < 4; ++t) {
                bf16x8 bf = *(const bf16x8*)&Ksh[(t * 16 + n15) * 264 + ks * 32 + quad * 8];
                s[t] = MFMA16(qf[ks], bf, s[t]);
            }
        }
        // online softmax over this wave's 16 private rows (row = quad*4 + r)
        float rmax[4], rs[4], alpha[4], p[4][4];
        #pragma unroll
        for (int r = 0; r < 4; ++r)
            rmax[r] = fmaxf(fmaxf(s[0][r], s[1][r]), fmaxf(s[2][r], s[3][r]));
        #pragma unroll
        for (int d = 1; d < 16; d <<= 1) {
            #pragma unroll
            for (int r = 0; r < 4; ++r) rmax[r] = fmaxf(rmax[r], __shfl_xor(rmax[r], d));
        }
        #pragma unroll
        for (int r = 0; r < 4; ++r) {
            float mn = fmaxf(m_[r], rmax[r] * SCL);
            alpha[r] = exp2f(m_[r] - mn);
            m_[r] = mn;
            rs[r] = 0.f;
        }
        #pragma unroll
        for (int t = 0; t < 4; ++t) {
            #pragma unroll
            for (int r = 0; r < 4; ++r) {
                p[t][r] = exp2f(s[t][r] * SCL - m_[r]);
                rs[r] += p[t][r];
            }
        }
        #pragma unroll
        for (int d = 1; d < 16; d <<= 1) {
            #pragma unroll
            for (int r = 0; r < 4; ++r) rs[r] += __shfl_xor(rs[r], d);
        }
        #pragma unroll
        for (int r = 0; r < 4; ++r) l_[r] = l_[r] * alpha[r] + rs[r];
        #pragma unroll
        for (int ct = 0; ct < 16; ++ct) {
            #pragma unroll
            for (int r = 0; r < 4; ++r) o[ct][r] *= alpha[r];
        }
        // C/D layout -> A layout round trip through wave-private LDS
        #pragma unroll
        for (int t = 0; t < 4; ++t) {
            #pragma unroll
            for (int r = 0; r < 4; ++r)
                Pw[(quad * 4 + r) * 72 + t * 16 + n15] = (bf16_t)p[t][r];
        }
        #pragma unroll
        for (int k2 = 0; k2 < 2; ++k2) {
            bf16x8 pa = *(const bf16x8*)&Pw[n15 * 72 + k2 * 32 + quad * 8];
            #pragma unroll
            for (int ct = 0; ct < 16; ++ct) {
                bf16x8 bv = *(const bf16x8*)&Vsh[(ct * 16 + n15) * 72 + k2 * 32 + quad * 8];
                o[ct] = MFMA16(pa, bv, o[ct]);
            }
        }
    }
    // write partials (unnormalized O, m, l) for this split
    int tokb = b * N + qt * 64 + w * 16 + quad * 4;
    #pragma unroll
    for (int ct = 0; ct < 16; ++ct) {
        #pragma unroll
        for (int r = 0; r < 4; ++r)
            Op[((size_t)(sp * T + tokb + r)) * D + ct * 16 + n15] = o[ct][r];
    }
    if (n15 == 0) {
        #pragma unroll
        for (int r = 0; r < 4; ++r) {
            Mp[sp * T + tokb + r] = m_[r];
            Lp[sp * T + tokb + r] = l_[r];
        }
    }
}

// ---- kernel 6: combine splits, normalize, transpose token->channel-major,
// ----           residual out = xn + gamma * O ------------------------------
__global__ void k_comb(const float* __restrict__ Op, const float* __restrict__ Mp,
                       const float* __restrict__ Lp, const float* __restrict__ gamma,
                       float* __restrict__ out) {
    __shared__ float wts[4][32];
    __shared__ float Ot[256 * 33];
    int blk = blockIdx.x;                // 256 blocks
    int b = blk >> 7, hw0 = (blk & 127) * 32;
    int tok0 = b * N + hw0;
    int tid = threadIdx.x;
    if (tid < 32) {
        float m0 = Mp[0 * T + tok0 + tid], m1 = Mp[1 * T + tok0 + tid];
        float m2 = Mp[2 * T + tok0 + tid], m3 = Mp[3 * T + tok0 + tid];
        float M = fmaxf(fmaxf(m0, m1), fmaxf(m2, m3));
        float w0 = exp2f(m0 - M), w1 = exp2f(m1 - M);
        float w2 = exp2f(m2 - M), w3 = exp2f(m3 - M);
        float Z = Lp[0 * T + tok0 + tid] * w0 + Lp[1 * T + tok0 + tid] * w1 +
                  Lp[2 * T + tok0 + tid] * w2 + Lp[3 * T + tok0 + tid] * w3;
        float iz = 1.0f / Z;
        wts[0][tid] = w0 * iz; wts[1][tid] = w1 * iz;
        wts[2][tid] = w2 * iz; wts[3][tid] = w3 * iz;
    }
    __syncthreads();
    #pragma unroll
    for (int i = 0; i < 32; ++i) {
        int idx = i * 256 + tid;
        int tk = idx >> 8, ch = idx & 255;
        size_t base = ((size_t)(tok0 + tk)) * D + ch;
        float acc = Op[0 * (size_t)T * D + base] * wts[0][tk]
                  + Op[1 * (size_t)T * D + base] * wts[1][tk]
                  + Op[2 * (size_t)T * D + base] * wts[2][tk]
                  + Op[3 * (size_t)T * D + base] * wts[3][tk];
        Ot[ch * 33 + tk] = acc;
    }
    __syncthreads();
    float g = gamma[0];
    float2* xo = (float2*)out;
    #pragma unroll
    for (int i = 0; i < 16; ++i) {
        int linear = i * 256 + tid;
        int c = linear >> 5, hwo = linear & 31;
        size_t idx = (size_t)(b * Cc + c) * N + hw0 + hwo;
        float2 v = xo[idx];
        v.x += g * Ot[c * 33 + hwo];
        v.y += g * Ot[(128 + c) * 33 + hwo];
        xo[idx] = v;
    }
}

extern "C" void kernel_launch(void* const* d_in, const int* in_sizes, int n_in,
                              void* d_out, int out_size, void* d_ws, size_t ws_size,
                              hipStream_t stream) {
    const float* x    = (const float*)d_in[0];
    const float* bn_w = (const float*)d_in[1];
    const float* bn_b = (const float*)d_in[2];
    const float* wq   = (const float*)d_in[3];
    const float* bq   = (const float*)d_in[4];
    const float* wk   = (const float*)d_in[5];
    const float* bk   = (const float*)d_in[6];
    const float* wv   = (const float*)d_in[7];
    const float* bv   = (const float*)d_in[8];
    const float* gam  = (const float*)d_in[9];
    float* out = (float*)d_out;

    char* ws = (char*)d_ws;
    size_t off = 0;
    auto alloc = [&](size_t bytes) -> void* {
        void* p = ws + off;
        off += (bytes + 255) & ~(size_t)255;
        return p;
    };
    float4* ss  = (float4*)alloc(Cc * sizeof(float4));
    bf16_t* XN  = (bf16_t*)alloc((size_t)T * D * 2);
    bf16_t* Wt  = (bf16_t*)alloc((size_t)768 * 256 * 2);
    float*  bt  = (float*)alloc(768 * 4);
    bf16_t* Qb  = (bf16_t*)alloc((size_t)T * D * 2);
    bf16_t* Kb  = (bf16_t*)alloc((size_t)T * D * 2);
    bf16_t* Vt  = (bf16_t*)alloc((size_t)T * D * 2);
    float*  Op  = (float*)alloc((size_t)4 * T * D * 4);
    float*  Mp  = (float*)alloc((size_t)4 * T * 4);
    float*  Lp  = (float*)alloc((size_t)4 * T * 4);

    k_bnstats<<<128, 256, 0, stream>>>(x, bn_w, bn_b, ss);
    k_norm<<<256, 256, 0, stream>>>(x, ss, out, XN);
    k_prep<<<768, 256, 0, stream>>>(wq, wk, wv, bq, bk, bv, Wt, bt);
    k_qkv<<<dim3(128, 12), 256, 0, stream>>>(XN, Wt, bt, Qb, Kb, Vt);
    k_attn<<<512, 256, 0, stream>>>(Qb, Kb, Vt, Op, Mp, Lp);
    k_comb<<<256, 256, 0, stream>>>(Op, Mp, Lp, gam, out);
}